// Round 4
// baseline (687.488 us; speedup 1.0000x reference)
//
#include <hip/hip_runtime.h>

typedef __bf16 bf16x8 __attribute__((ext_vector_type(8)));
typedef float f32x4 __attribute__((ext_vector_type(4)));
typedef unsigned short us8 __attribute__((ext_vector_type(8)));
typedef unsigned short us4 __attribute__((ext_vector_type(4)));
typedef unsigned int u32;

#define HIDN 768
#define NHEAD 12
#define HDIM 64
#define FFDIM 3072
#define NCAND 8

__device__ __forceinline__ float bf2f(unsigned short u) {
    union { unsigned int i; float f; } x; x.i = ((unsigned int)u) << 16; return x.f;
}
__device__ __forceinline__ unsigned short f2bf(float f) {
    __bf16 h = (__bf16)f;
    return __builtin_bit_cast(unsigned short, h);
}

typedef const __attribute__((address_space(1))) u32* gas_p;
typedef __attribute__((address_space(3))) u32* las_p;
__device__ __forceinline__ void load_lds16(const unsigned short* g, unsigned short* l) {
    __builtin_amdgcn_global_load_lds((gas_p)(const void*)g, (las_p)(void*)l, 16, 0, 0);
}

// ---------------- conversion kernels ----------------
__global__ __launch_bounds__(256) void cvt_f2b(const float* __restrict__ src,
                                               unsigned short* __restrict__ dst, long n4) {
    long i = (long)blockIdx.x * 256 + threadIdx.x;
    if (i >= n4) return;
    float4 f = ((const float4*)src)[i];
    us4 o; o[0] = f2bf(f.x); o[1] = f2bf(f.y); o[2] = f2bf(f.z); o[3] = f2bf(f.w);
    *(us4*)&dst[i * 4] = o;
}

// Wk2[h][j][d] = Wk[(h*64+d)*768 + j]  — coalesced via LDS transpose tile
__global__ __launch_bounds__(256) void cvt_wk(const float* __restrict__ Wk,
                                              unsigned short* __restrict__ Wk2) {
    __shared__ float t[64][65];
    const int bx = blockIdx.x;
    const int h = bx / (HIDN / 64), jt = bx % (HIDN / 64);
    const int tid = threadIdx.x;
    int rj = tid & 63, rd = tid >> 6;
    for (int d = rd; d < 64; d += 4)
        t[d][rj] = Wk[(long)(h * 64 + d) * HIDN + jt * 64 + rj];
    __syncthreads();
    int wd = tid & 63, wj = tid >> 6;
    for (int j = wj; j < 64; j += 4)
        Wk2[((long)h * HIDN + jt * 64 + j) * 64 + wd] = f2bf(t[wd][j]);
}

// ---------------- mask dtype detection (parallel) ----------------
__global__ void zero_flags(int* __restrict__ f) {
    if (threadIdx.x < 3) f[threadIdx.x] = 0;
}
// flags[0]: nz at j%4==1 ; flags[1]: nz at j%4 in {2,3} ; flags[2]: nz at j%8==4
__global__ __launch_bounds__(256) void mask_scan(const unsigned char* __restrict__ m,
                                                 int nbytes, int* __restrict__ flags) {
    int a0 = 0, a1 = 0, a2 = 0;
    for (int i = blockIdx.x * 256 + threadIdx.x; i < nbytes; i += gridDim.x * 256) {
        if (m[i]) {
            int r4 = i & 3, r8 = i & 7;
            if (r4 == 1) a0 = 1;
            if (r4 >= 2) a1 = 1;
            if (r8 == 4) a2 = 1;
        }
    }
    if (a0) atomicOr(&flags[0], 1);
    if (a1) atomicOr(&flags[1], 1);
    if (a2) atomicOr(&flags[2], 1);
}

// ============ m97-style GEMM: C(M,N) = A(M,K) @ B(N,K)^T + bias ============
template <bool OUT_BF16, bool GELU, int AI>
__global__ __launch_bounds__(256) void gemm128(
    const unsigned short* __restrict__ A, const unsigned short* __restrict__ B,
    void* __restrict__ Cv, const float* __restrict__ bias,
    int K, int lda, int ldb, int ldc,
    long a_z, long b_z, long c_z) {
    const int z = blockIdx.z;
    A += (long)z * a_z;
    B += (long)z * b_z;
    const int tid = threadIdx.x;
    const int m0 = blockIdx.y * (AI * 32), n0 = blockIdx.x * 128;
    __shared__ __attribute__((aligned(16))) unsigned short As[AI * 32 * 64];
    __shared__ __attribute__((aligned(16))) unsigned short Bs[128 * 64];
    f32x4 acc[AI][4] = {};
    const int lane = tid & 63, w = tid >> 6;
    const int wm = w & 1, wn = w >> 1;

    for (int k0 = 0; k0 < K; k0 += 64) {
#pragma unroll
        for (int i = 0; i < AI; i++) {
            int c = i * 256 + tid;
            int row = c >> 3;
            int g = (c & 7) ^ (row & 7);
            load_lds16(&A[(long)(m0 + row) * lda + k0 + g * 8], &As[c * 8]);
        }
#pragma unroll
        for (int i = 0; i < 4; i++) {
            int c = i * 256 + tid;
            int row = c >> 3;
            int g = (c & 7) ^ (row & 7);
            load_lds16(&B[(long)(n0 + row) * ldb + k0 + g * 8], &Bs[c * 8]);
        }
        __syncthreads();
#pragma unroll
        for (int kk = 0; kk < 64; kk += 32) {
            const int gc = (kk >> 3) + (lane >> 4);
            bf16x8 af[AI], bfr[4];
#pragma unroll
            for (int i = 0; i < AI; i++) {
                int r = wm * (AI * 16) + i * 16 + (lane & 15);
                af[i] = *(const bf16x8*)&As[r * 64 + ((gc ^ (r & 7)) << 3)];
            }
#pragma unroll
            for (int j = 0; j < 4; j++) {
                int r = wn * 64 + j * 16 + (lane & 15);
                bfr[j] = *(const bf16x8*)&Bs[r * 64 + ((gc ^ (r & 7)) << 3)];
            }
#pragma unroll
            for (int i = 0; i < AI; i++)
#pragma unroll
                for (int j = 0; j < 4; j++)
                    acc[i][j] = __builtin_amdgcn_mfma_f32_16x16x32_bf16(af[i], bfr[j], acc[i][j], 0, 0, 0);
        }
        __syncthreads();
    }

    float* Cf = (float*)Cv;
    unsigned short* Ch = (unsigned short*)Cv;
    const long cbase = (long)z * c_z;
#pragma unroll
    for (int i = 0; i < AI; i++)
#pragma unroll
        for (int j = 0; j < 4; j++) {
            int col = n0 + wn * 64 + j * 16 + (lane & 15);
            int rbase = m0 + wm * (AI * 16) + i * 16 + ((lane >> 4) * 4);
            float bb = bias ? bias[col] : 0.f;
#pragma unroll
            for (int r = 0; r < 4; r++) {
                int row = rbase + r;
                float v = acc[i][j][r] + bb;
                if (GELU) v = 0.5f * v * (1.f + erff(v * 0.70710678118654752f));
                long off = cbase + (long)row * ldc + col;
                if (OUT_BF16) Ch[off] = f2bf(v);
                else Cf[off] = v;
            }
        }
}

// ======== N=64 GEMM (G5): C(:, z*64 + [0,64)) = A_z(M,K) @ B_z(64,K)^T ========
// gemm128-style staging: global_load_lds width-16, XOR-swizzled chunks.
// Wave layout 2M x 2N (wave tile AI*16 x 32). bf16 out, +bias, *flag.
template <int AI>
__global__ __launch_bounds__(256) void gemm_n64(
    const unsigned short* __restrict__ A, const unsigned short* __restrict__ B,
    unsigned short* __restrict__ C, const float* __restrict__ bias,
    const float* __restrict__ flag,
    int K, int lda, int ldc, long a_z, long b_z, int c_col_z, int bias_z) {
    const int z = blockIdx.z;
    A += (long)z * a_z;
    B += (long)z * b_z;
    const int tid = threadIdx.x;
    const int m0 = blockIdx.y * (AI * 32);
    __shared__ __attribute__((aligned(16))) unsigned short As[AI * 32 * 64];
    __shared__ __attribute__((aligned(16))) unsigned short Bs[64 * 64];
    f32x4 acc[AI][2] = {};
    const int lane = tid & 63, w = tid >> 6;
    const int wm = w & 1, wn = w >> 1;

    for (int k0 = 0; k0 < K; k0 += 64) {
#pragma unroll
        for (int i = 0; i < AI; i++) {
            int c = i * 256 + tid;
            int row = c >> 3;
            int g = (c & 7) ^ (row & 7);
            load_lds16(&A[(long)(m0 + row) * lda + k0 + g * 8], &As[c * 8]);
        }
#pragma unroll
        for (int i = 0; i < 2; i++) {
            int c = i * 256 + tid;
            int row = c >> 3;
            int g = (c & 7) ^ (row & 7);
            load_lds16(&B[(long)row * K + k0 + g * 8], &Bs[c * 8]);
        }
        __syncthreads();
#pragma unroll
        for (int kk = 0; kk < 64; kk += 32) {
            const int gc = (kk >> 3) + (lane >> 4);
            bf16x8 af[AI], bfr[2];
#pragma unroll
            for (int i = 0; i < AI; i++) {
                int r = wm * (AI * 16) + i * 16 + (lane & 15);
                af[i] = *(const bf16x8*)&As[r * 64 + ((gc ^ (r & 7)) << 3)];
            }
#pragma unroll
            for (int j = 0; j < 2; j++) {
                int r = wn * 32 + j * 16 + (lane & 15);
                bfr[j] = *(const bf16x8*)&Bs[r * 64 + ((gc ^ (r & 7)) << 3)];
            }
#pragma unroll
            for (int i = 0; i < AI; i++)
#pragma unroll
                for (int j = 0; j < 2; j++)
                    acc[i][j] = __builtin_amdgcn_mfma_f32_16x16x32_bf16(af[i], bfr[j], acc[i][j], 0, 0, 0);
        }
        __syncthreads();
    }

#pragma unroll
    for (int i = 0; i < AI; i++)
#pragma unroll
        for (int j = 0; j < 2; j++) {
            int col = wn * 32 + j * 16 + (lane & 15);
            int rbase = m0 + wm * (AI * 16) + i * 16 + ((lane >> 4) * 4);
            float bb = bias[(long)z * bias_z + col];
#pragma unroll
            for (int r = 0; r < 4; r++) {
                int row = rbase + r;
                float v = (acc[i][j][r] + bb) * flag[row];
                C[(long)row * ldc + (long)z * c_col_z + col] = f2bf(v);
            }
        }
}

// ---------------- qbk[t,h] = sum_d q[t,h,d] * bk[h*64+d] ----------------
__global__ __launch_bounds__(256) void qbk_kernel(const unsigned short* __restrict__ Qb,
                                                  const float* __restrict__ bk,
                                                  float* __restrict__ qbk, long npair) {
    int lane = threadIdx.x & 63, w = threadIdx.x >> 6;
    long p = (long)blockIdx.x * 4 + w;
    if (p >= npair) return;
    long t = p / 12;
    int h = (int)(p - t * 12);
    float v = bf2f(Qb[t * HIDN + h * 64 + lane]) * bk[h * 64 + lane];
    for (int o = 32; o; o >>= 1) v += __shfl_down(v, o);
    if (lane == 0) qbk[p] = v;
}

// ---------------- fused attention v5 ----------------
// LDS diet (5 blocks/CU):
//   c_s : 8 rows x LDP(=776) bf16 (padded, staged via VALU convert)  = 12416 B
//   qk_s: 12 rows x 768 bf16, UNPADDED, 16B-chunk XOR-swizzle        = 18432 B
//         (staged async via global_load_lds w/ pre-swizzled source — m173)
//   scr : 16x16 f32 scores, re-used for softmax weights              =  1024 B
// MFMA fragment rows 12-15 / 8-15 are clamped to the last valid row instead
// of pad rows (garbage lands only in discarded C rows/cols).
// The fp32 candidate values loaded in phase 1b are CARRIED IN REGISTERS
// (cf[6] float4) and written to the fp32 repack region in phase 3 — no LDS
// re-read, no bf16 round-trip; cw consumes exact fp32 c.
#define LDP 776
__global__ __launch_bounds__(256) void attn_kernel(
    const float* __restrict__ cands, unsigned short* __restrict__ qkcw,
    const void* __restrict__ maskp, const int* __restrict__ flags,
    const float* __restrict__ qbk, float* __restrict__ allm, long t0) {
    const int tid = threadIdx.x;
    const long tl = blockIdx.x;
    const long t = t0 + tl;
    __shared__ __attribute__((aligned(16))) unsigned short buf[8 * LDP + 12 * HIDN];
    unsigned short* c_s = buf;
    unsigned short* qk_s = buf + 8 * LDP;
    __shared__ float scr[16][16];
    __shared__ int msk[NCAND];
    __shared__ float qb_s[NHEAD];

    // ---- phase 1a: issue async qk stage first (overlaps with c convert) ----
    const unsigned short* qsrc = qkcw + tl * (NHEAD * HIDN);
#pragma unroll
    for (int p = 0; p < 5; p++) {
        int i = tid + p * 256;  // 16B chunk index, 1152 total
        if (i < NHEAD * HIDN / 8) {
            int row = i / 96, cc = i - row * 96;
            int g = (cc & ~7) | ((cc & 7) ^ (row & 7));
            load_lds16(&qsrc[row * HIDN + g * 8], &qk_s[i * 8]);
        }
    }
    // ---- phase 1b: c fp32 global -> bf16 LDS, keep fp32 in registers ----
    const float4* c4 = (const float4*)(cands + t * NCAND * HIDN);
    float4 cf[6];
#pragma unroll
    for (int p = 0; p < 6; p++) {
        int i = tid + p * 256;  // 1536 float4s
        int n = i / 192, j4 = (i - n * 192) * 4;
        float4 f = c4[i];
        cf[p] = f;
        us4 o; o[0] = f2bf(f.x); o[1] = f2bf(f.y); o[2] = f2bf(f.z); o[3] = f2bf(f.w);
        *(us4*)&c_s[n * LDP + j4] = o;
    }
    if (tid < NCAND) {
        int mm = flags[0] ? 1 : (flags[1] ? 2 : (flags[2] ? 0 : 3));
        long mi = t * NCAND + tid;
        int mv;
        if (mm == 1)      mv = ((const unsigned char*)maskp)[mi] != 0;
        else if (mm == 2) mv = ((const float*)maskp)[mi] != 0.f;
        else if (mm == 3) mv = ((const long long*)maskp)[mi] != 0;
        else              mv = ((const int*)maskp)[mi] != 0;
        msk[tid] = mv;
    }
    if (tid >= 64 && tid < 64 + NHEAD) qb_s[tid - 64] = qbk[tl * NHEAD + (tid - 64)];
    __syncthreads();

    const int lane = tid & 63, w = tid >> 6;

    // ---- phase 2: scores via MFMA on wave 0: C[h][n] = qk[h,:] . c[n,:] ----
    if (w == 0) {
        int ar = lane & 15; if (ar > 11) ar = 11;  // clamp: rows 12-15 -> garbage C rows
        int br = lane & 15; if (br > 7) br = 7;    // clamp: cols 8-15 -> garbage C cols
        const int kq = lane >> 4;
        const unsigned short* brow = &c_s[br * LDP + kq * 8];
        f32x4 a0 = {}, a1 = {};
#pragma unroll
        for (int k0 = 0; k0 < HIDN; k0 += 64) {
            int c1 = (k0 >> 3) + kq, c2 = c1 + 4;
            int g1 = (c1 & ~7) | ((c1 & 7) ^ (ar & 7));
            int g2 = (c2 & ~7) | ((c2 & 7) ^ (ar & 7));
            bf16x8 afa = *(const bf16x8*)&qk_s[ar * HIDN + g1 * 8];
            bf16x8 afb = *(const bf16x8*)&qk_s[ar * HIDN + g2 * 8];
            bf16x8 bfa = *(const bf16x8*)&brow[k0];
            bf16x8 bfb = *(const bf16x8*)&brow[k0 + 32];
            a0 = __builtin_amdgcn_mfma_f32_16x16x32_bf16(afa, bfa, a0, 0, 0, 0);
            a1 = __builtin_amdgcn_mfma_f32_16x16x32_bf16(afb, bfb, a1, 0, 0, 0);
        }
        int n = lane & 15;
#pragma unroll
        for (int r = 0; r < 4; r++) {
            int h = (lane >> 4) * 4 + r;
            scr[h][n] = a0[r] + a1[r];
        }
    }
    if (tid == 64) {
        int a = 1;
        for (int n = 0; n < NCAND; n++) a &= msk[n];
        allm[tl] = a ? 0.f : 1.f;
    }
    __syncthreads();

    // ---- phase 3: softmax (12 threads) + fp32 repack of c from registers ----
    if (tid < NHEAD) {
        int h = tid;
        float sv[NCAND], sm = 0.f, mx = -1e30f;
        for (int n = 0; n < NCAND; n++) {
            sv[n] = msk[n] ? 1e-10f : (scr[h][n] + qb_s[h]) * 0.125f;
            mx = fmaxf(mx, sv[n]);
        }
        for (int n = 0; n < NCAND; n++) { sv[n] = expf(sv[n] - mx); sm += sv[n]; }
        float inv = 1.f / sm;
        for (int n = 0; n < NCAND; n++) scr[h][n] = sv[n] * inv;  // weights overlay scores
    }
    // c32[n*768 + j] linear == chunk index * 4 (since 768 = 192*4)
    float* c32 = (float*)buf;  // 6144 floats = 24576 B <= 30848 B (qk region dead)
#pragma unroll
    for (int p = 0; p < 6; p++) {
        int i = tid + p * 256;
        *(float4*)&c32[i * 4] = cf[p];
    }
    __syncthreads();

    // ---- phase 4: cw: out[h][j..j+7] = sum_n w[h][n] * c32[n][j..j+7] ----
    unsigned short* out = qkcw + tl * (NHEAD * HIDN);
#pragma unroll
    for (int p = 0; p < 5; p++) {
        int i = tid + p * 256;
        if (i < NHEAD * HIDN / 8) {
            int h = i / 96, j8 = (i - h * 96) * 8;
            f32x4 acc0 = {}, acc1 = {};
#pragma unroll
            for (int n = 0; n < NCAND; n++) {
                float a = scr[h][n];
                f32x4 v0 = *(const f32x4*)&c32[n * HIDN + j8];
                f32x4 v1 = *(const f32x4*)&c32[n * HIDN + j8 + 4];
#pragma unroll
                for (int k = 0; k < 4; k++) { acc0[k] += a * v0[k]; acc1[k] += a * v1[k]; }
            }
            us8 o;
#pragma unroll
            for (int k = 0; k < 4; k++) { o[k] = f2bf(acc0[k]); o[4 + k] = f2bf(acc1[k]); }
            *(us8*)&out[i * 8] = o;
        }
    }
}

// ---------------- residual + layernorm ----------------
__global__ __launch_bounds__(256) void ln_kernel(float* __restrict__ io, const float* __restrict__ x,
                                                 const float* __restrict__ gamma,
                                                 const float* __restrict__ beta, long t0) {
    const int tid = threadIdx.x;
    const long tl = blockIdx.x;
    const long t = t0 + tl;
    float* row = io + tl * HIDN;
    const float* xr = x + t * HIDN;
    float v[3];
#pragma unroll
    for (int i = 0; i < 3; i++) v[i] = row[tid + i * 256] + xr[tid + i * 256];
    __shared__ float red[4];
    const int lane = tid & 63, w = tid >> 6;
    float s = v[0] + v[1] + v[2];
    for (int o = 32; o; o >>= 1) s += __shfl_down(s, o);
    if (lane == 0) red[w] = s;
    __syncthreads();
    float mu = (red[0] + red[1] + red[2] + red[3]) * (1.f / HIDN);
    __syncthreads();
    float d0 = v[0] - mu, d1 = v[1] - mu, d2 = v[2] - mu;
    float q = d0 * d0 + d1 * d1 + d2 * d2;
    for (int o = 32; o; o >>= 1) q += __shfl_down(q, o);
    if (lane == 0) red[w] = q;
    __syncthreads();
    float var = (red[0] + red[1] + red[2] + red[3]) * (1.f / HIDN);
    float inv = rsqrtf(var + 1e-12f);
#pragma unroll
    for (int i = 0; i < 3; i++) {
        int j = tid + i * 256;
        row[j] = (v[i] - mu) * inv * gamma[j] + beta[j];
    }
}

// ---------------- launcher ----------------
extern "C" void kernel_launch(void* const* d_in, const int* in_sizes, int n_in,
                              void* d_out, int out_size, void* d_ws, size_t ws_size,
                              hipStream_t stream) {
    const float* x     = (const float*)d_in[0];
    const float* cands = (const float*)d_in[1];
    const void*  maskp = d_in[2];
    const float* Wq = (const float*)d_in[3];
    const float* bq = (const float*)d_in[4];
    const float* Wk = (const float*)d_in[5];
    const float* bk = (const float*)d_in[6];
    const float* Wv = (const float*)d_in[7];
    const float* bv = (const float*)d_in[8];
    const float* Wt = (const float*)d_in[9];
    const float* bt = (const float*)d_in[10];
    const float* Wc = (const float*)d_in[11];
    const float* bc = (const float*)d_in[12];
    const float* gamma = (const float*)d_in[13];
    const float* beta  = (const float*)d_in[14];
    float* out = (float*)d_out;

    const long T = (long)in_sizes[0] / HIDN;  // 8192

    char* p = (char*)d_ws;
    auto alloc = [&](size_t bytes) -> char* {
        char* r = p;
        p += (bytes + 255) & ~(size_t)255;
        return r;
    };
    unsigned short* Wqb  = (unsigned short*)alloc((size_t)HIDN * HIDN * 2);
    unsigned short* Wk2b = (unsigned short*)alloc((size_t)HIDN * HIDN * 2);
    unsigned short* Wvb  = (unsigned short*)alloc((size_t)HIDN * HIDN * 2);
    unsigned short* Wtb  = (unsigned short*)alloc((size_t)FFDIM * HIDN * 2);
    unsigned short* Wcb  = (unsigned short*)alloc((size_t)HIDN * FFDIM * 2);
    int* flags = (int*)alloc(256);
    size_t fixed = (size_t)(p - (char*)d_ws);

    long TC = T;
    auto chunk_bytes = [&](long tc) -> size_t {
        return (size_t)tc * (HIDN * 2 + HIDN * 2 + NHEAD * 4 + 4 +
                             HIDN * 2 + NHEAD * HIDN * 2) + 8 * 256;
    };
    while (TC > 512 && fixed + chunk_bytes(TC) > ws_size) TC >>= 1;

    unsigned short* Xb   = (unsigned short*)alloc((size_t)TC * HIDN * 2);
    unsigned short* Qb   = (unsigned short*)alloc((size_t)TC * HIDN * 2);
    float* qbkb          = (float*)alloc((size_t)TC * NHEAD * 4);
    float* allm          = (float*)alloc((size_t)TC * 4);
    unsigned short* CTXb = (unsigned short*)alloc((size_t)TC * HIDN * 2);
    unsigned short* BIG  = (unsigned short*)alloc((size_t)TC * NHEAD * HIDN * 2);

    {
        long n4;
        n4 = (long)HIDN * HIDN / 4;
        cvt_f2b<<<dim3((n4 + 255) / 256), 256, 0, stream>>>(Wq, Wqb, n4);
        cvt_f2b<<<dim3((n4 + 255) / 256), 256, 0, stream>>>(Wv, Wvb, n4);
        n4 = (long)FFDIM * HIDN / 4;
        cvt_f2b<<<dim3((n4 + 255) / 256), 256, 0, stream>>>(Wt, Wtb, n4);
        cvt_f2b<<<dim3((n4 + 255) / 256), 256, 0, stream>>>(Wc, Wcb, n4);
        cvt_wk<<<dim3(NHEAD * (HIDN / 64)), 256, 0, stream>>>(Wk, Wk2b);
        zero_flags<<<dim3(1), 64, 0, stream>>>(flags);
        mask_scan<<<dim3(256), 256, 0, stream>>>((const unsigned char*)maskp,
                                                 (int)(T * NCAND), flags);
    }

    for (long t0 = 0; t0 < T; t0 += TC) {
        long n4 = TC * HIDN / 4;
        cvt_f2b<<<dim3((n4 + 255) / 256), 256, 0, stream>>>(x + t0 * HIDN, Xb, n4);

        // G1: Q = X @ Wq^T + bq  (128x128 tile)
        gemm128<true, false, 4><<<dim3(HIDN / 128, TC / 128, 1), 256, 0, stream>>>(
            Xb, Wqb, Qb, bq, HIDN, HIDN, HIDN, HIDN, 0, 0, 0);

        qbk_kernel<<<dim3((TC * NHEAD + 3) / 4), 256, 0, stream>>>(Qb, bk, qbkb, TC * NHEAD);

        // G2: qk_h = Q_h @ Wk_h  (per head, K=64; 256x128 tile amortizes staging)
        gemm128<true, false, 8><<<dim3(HIDN / 128, TC / 256, NHEAD), 256, 0, stream>>>(
            Qb, Wk2b, BIG, nullptr, HDIM, HIDN, HDIM, NHEAD * HIDN,
            HDIM, (long)HIDN * HDIM, HIDN);

        attn_kernel<<<dim3(TC), 256, 0, stream>>>(cands, BIG, maskp, flags, qbkb, allm, t0);

        // G5: ctx_h = cw_h @ Wv_h^T + bv_h (per head, N=64) — 128x64 async-staged
        gemm_n64<4><<<dim3(1, TC / 128, NHEAD), 256, 0, stream>>>(
            BIG, Wvb, CTXb, bv, allm, HIDN, NHEAD * HIDN, HIDN,
            HIDN, (long)HDIM * HIDN, HDIM, HDIM);

        // G6: h1 = gelu(ctx @ Wt^T + bt)
        gemm128<true, true, 4><<<dim3(FFDIM / 128, TC / 128, 1), 256, 0, stream>>>(
            CTXb, Wtb, BIG, bt, HIDN, HIDN, HIDN, FFDIM, 0, 0, 0);

        // G7: out = h1 @ Wc^T + bc (fp32)  (128x128 tile)
        gemm128<false, false, 4><<<dim3(HIDN / 128, TC / 128, 1), 256, 0, stream>>>(
            BIG, Wcb, out + t0 * HIDN, bc, FFDIM, FFDIM, FFDIM, HIDN, 0, 0, 0);

        ln_kernel<<<dim3(TC), 256, 0, stream>>>(out + t0 * HIDN, x, gamma, beta, t0);
    }
}

// Round 5
// 625.840 us; speedup vs baseline: 1.0985x; 1.0985x over previous
//
#include <hip/hip_runtime.h>

typedef __bf16 bf16x8 __attribute__((ext_vector_type(8)));
typedef float f32x4 __attribute__((ext_vector_type(4)));
typedef unsigned short us8 __attribute__((ext_vector_type(8)));
typedef unsigned short us4 __attribute__((ext_vector_type(4)));
typedef unsigned int u32;

#define HIDN 768
#define NHEAD 12
#define HDIM 64
#define FFDIM 3072
#define NCAND 8

__device__ __forceinline__ float bf2f(unsigned short u) {
    union { unsigned int i; float f; } x; x.i = ((unsigned int)u) << 16; return x.f;
}
__device__ __forceinline__ unsigned short f2bf(float f) {
    __bf16 h = (__bf16)f;
    return __builtin_bit_cast(unsigned short, h);
}

typedef const __attribute__((address_space(1))) u32* gas_p;
typedef __attribute__((address_space(3))) u32* las_p;
__device__ __forceinline__ void load_lds16(const unsigned short* g, unsigned short* l) {
    __builtin_amdgcn_global_load_lds((gas_p)(const void*)g, (las_p)(void*)l, 16, 0, 0);
}

// ---------------- conversion kernels ----------------
__global__ __launch_bounds__(256) void cvt_f2b(const float* __restrict__ src,
                                               unsigned short* __restrict__ dst, long n4) {
    long i = (long)blockIdx.x * 256 + threadIdx.x;
    if (i >= n4) return;
    float4 f = ((const float4*)src)[i];
    us4 o; o[0] = f2bf(f.x); o[1] = f2bf(f.y); o[2] = f2bf(f.z); o[3] = f2bf(f.w);
    *(us4*)&dst[i * 4] = o;
}

// Wk2[h][j][d] = Wk[(h*64+d)*768 + j]  — coalesced via LDS transpose tile
__global__ __launch_bounds__(256) void cvt_wk(const float* __restrict__ Wk,
                                              unsigned short* __restrict__ Wk2) {
    __shared__ float t[64][65];
    const int bx = blockIdx.x;
    const int h = bx / (HIDN / 64), jt = bx % (HIDN / 64);
    const int tid = threadIdx.x;
    int rj = tid & 63, rd = tid >> 6;
    for (int d = rd; d < 64; d += 4)
        t[d][rj] = Wk[(long)(h * 64 + d) * HIDN + jt * 64 + rj];
    __syncthreads();
    int wd = tid & 63, wj = tid >> 6;
    for (int j = wj; j < 64; j += 4)
        Wk2[((long)h * HIDN + jt * 64 + j) * 64 + wd] = f2bf(t[wd][j]);
}

// ---------------- mask dtype detection (parallel) ----------------
__global__ void zero_flags(int* __restrict__ f) {
    if (threadIdx.x < 3) f[threadIdx.x] = 0;
}
// flags[0]: nz at j%4==1 ; flags[1]: nz at j%4 in {2,3} ; flags[2]: nz at j%8==4
__global__ __launch_bounds__(256) void mask_scan(const unsigned char* __restrict__ m,
                                                 int nbytes, int* __restrict__ flags) {
    int a0 = 0, a1 = 0, a2 = 0;
    for (int i = blockIdx.x * 256 + threadIdx.x; i < nbytes; i += gridDim.x * 256) {
        if (m[i]) {
            int r4 = i & 3, r8 = i & 7;
            if (r4 == 1) a0 = 1;
            if (r4 >= 2) a1 = 1;
            if (r8 == 4) a2 = 1;
        }
    }
    if (a0) atomicOr(&flags[0], 1);
    if (a1) atomicOr(&flags[1], 1);
    if (a2) atomicOr(&flags[2], 1);
}

// ============ m97-style GEMM: C(M,N) = A(M,K) @ B(N,K)^T + bias ============
template <bool OUT_BF16, bool GELU, int AI>
__global__ __launch_bounds__(256) void gemm128(
    const unsigned short* __restrict__ A, const unsigned short* __restrict__ B,
    void* __restrict__ Cv, const float* __restrict__ bias,
    int K, int lda, int ldb, int ldc,
    long a_z, long b_z, long c_z) {
    const int z = blockIdx.z;
    A += (long)z * a_z;
    B += (long)z * b_z;
    const int tid = threadIdx.x;
    const int m0 = blockIdx.y * (AI * 32), n0 = blockIdx.x * 128;
    __shared__ __attribute__((aligned(16))) unsigned short As[AI * 32 * 64];
    __shared__ __attribute__((aligned(16))) unsigned short Bs[128 * 64];
    f32x4 acc[AI][4] = {};
    const int lane = tid & 63, w = tid >> 6;
    const int wm = w & 1, wn = w >> 1;

    for (int k0 = 0; k0 < K; k0 += 64) {
#pragma unroll
        for (int i = 0; i < AI; i++) {
            int c = i * 256 + tid;
            int row = c >> 3;
            int g = (c & 7) ^ (row & 7);
            load_lds16(&A[(long)(m0 + row) * lda + k0 + g * 8], &As[c * 8]);
        }
#pragma unroll
        for (int i = 0; i < 4; i++) {
            int c = i * 256 + tid;
            int row = c >> 3;
            int g = (c & 7) ^ (row & 7);
            load_lds16(&B[(long)(n0 + row) * ldb + k0 + g * 8], &Bs[c * 8]);
        }
        __syncthreads();
#pragma unroll
        for (int kk = 0; kk < 64; kk += 32) {
            const int gc = (kk >> 3) + (lane >> 4);
            bf16x8 af[AI], bfr[4];
#pragma unroll
            for (int i = 0; i < AI; i++) {
                int r = wm * (AI * 16) + i * 16 + (lane & 15);
                af[i] = *(const bf16x8*)&As[r * 64 + ((gc ^ (r & 7)) << 3)];
            }
#pragma unroll
            for (int j = 0; j < 4; j++) {
                int r = wn * 64 + j * 16 + (lane & 15);
                bfr[j] = *(const bf16x8*)&Bs[r * 64 + ((gc ^ (r & 7)) << 3)];
            }
#pragma unroll
            for (int i = 0; i < AI; i++)
#pragma unroll
                for (int j = 0; j < 4; j++)
                    acc[i][j] = __builtin_amdgcn_mfma_f32_16x16x32_bf16(af[i], bfr[j], acc[i][j], 0, 0, 0);
        }
        __syncthreads();
    }

    float* Cf = (float*)Cv;
    unsigned short* Ch = (unsigned short*)Cv;
    const long cbase = (long)z * c_z;
#pragma unroll
    for (int i = 0; i < AI; i++)
#pragma unroll
        for (int j = 0; j < 4; j++) {
            int col = n0 + wn * 64 + j * 16 + (lane & 15);
            int rbase = m0 + wm * (AI * 16) + i * 16 + ((lane >> 4) * 4);
            float bb = bias ? bias[col] : 0.f;
#pragma unroll
            for (int r = 0; r < 4; r++) {
                int row = rbase + r;
                float v = acc[i][j][r] + bb;
                if (GELU) v = 0.5f * v * (1.f + erff(v * 0.70710678118654752f));
                long off = cbase + (long)row * ldc + col;
                if (OUT_BF16) Ch[off] = f2bf(v);
                else Cf[off] = v;
            }
        }
}

// ======== N=64 GEMM (G5): C(:, z*64 + [0,64)) = A_z(M,K) @ B_z(64,K)^T ========
// gemm128-style staging: global_load_lds width-16, XOR-swizzled chunks.
// Wave layout 2M x 2N (wave tile AI*16 x 32). bf16 out, +bias, *flag.
template <int AI>
__global__ __launch_bounds__(256) void gemm_n64(
    const unsigned short* __restrict__ A, const unsigned short* __restrict__ B,
    unsigned short* __restrict__ C, const float* __restrict__ bias,
    const float* __restrict__ flag,
    int K, int lda, int ldc, long a_z, long b_z, int c_col_z, int bias_z) {
    const int z = blockIdx.z;
    A += (long)z * a_z;
    B += (long)z * b_z;
    const int tid = threadIdx.x;
    const int m0 = blockIdx.y * (AI * 32);
    __shared__ __attribute__((aligned(16))) unsigned short As[AI * 32 * 64];
    __shared__ __attribute__((aligned(16))) unsigned short Bs[64 * 64];
    f32x4 acc[AI][2] = {};
    const int lane = tid & 63, w = tid >> 6;
    const int wm = w & 1, wn = w >> 1;

    for (int k0 = 0; k0 < K; k0 += 64) {
#pragma unroll
        for (int i = 0; i < AI; i++) {
            int c = i * 256 + tid;
            int row = c >> 3;
            int g = (c & 7) ^ (row & 7);
            load_lds16(&A[(long)(m0 + row) * lda + k0 + g * 8], &As[c * 8]);
        }
#pragma unroll
        for (int i = 0; i < 2; i++) {
            int c = i * 256 + tid;
            int row = c >> 3;
            int g = (c & 7) ^ (row & 7);
            load_lds16(&B[(long)row * K + k0 + g * 8], &Bs[c * 8]);
        }
        __syncthreads();
#pragma unroll
        for (int kk = 0; kk < 64; kk += 32) {
            const int gc = (kk >> 3) + (lane >> 4);
            bf16x8 af[AI], bfr[2];
#pragma unroll
            for (int i = 0; i < AI; i++) {
                int r = wm * (AI * 16) + i * 16 + (lane & 15);
                af[i] = *(const bf16x8*)&As[r * 64 + ((gc ^ (r & 7)) << 3)];
            }
#pragma unroll
            for (int j = 0; j < 2; j++) {
                int r = wn * 32 + j * 16 + (lane & 15);
                bfr[j] = *(const bf16x8*)&Bs[r * 64 + ((gc ^ (r & 7)) << 3)];
            }
#pragma unroll
            for (int i = 0; i < AI; i++)
#pragma unroll
                for (int j = 0; j < 2; j++)
                    acc[i][j] = __builtin_amdgcn_mfma_f32_16x16x32_bf16(af[i], bfr[j], acc[i][j], 0, 0, 0);
        }
        __syncthreads();
    }

#pragma unroll
    for (int i = 0; i < AI; i++)
#pragma unroll
        for (int j = 0; j < 2; j++) {
            int col = wn * 32 + j * 16 + (lane & 15);
            int rbase = m0 + wm * (AI * 16) + i * 16 + ((lane >> 4) * 4);
            float bb = bias[(long)z * bias_z + col];
#pragma unroll
            for (int r = 0; r < 4; r++) {
                int row = rbase + r;
                float v = (acc[i][j][r] + bb) * flag[row];
                C[(long)row * ldc + (long)z * c_col_z + col] = f2bf(v);
            }
        }
}

// ---------------- qbk[t,h] = sum_d q[t,h,d] * bk[h*64+d] ----------------
__global__ __launch_bounds__(256) void qbk_kernel(const unsigned short* __restrict__ Qb,
                                                  const float* __restrict__ bk,
                                                  float* __restrict__ qbk, long npair) {
    int lane = threadIdx.x & 63, w = threadIdx.x >> 6;
    long p = (long)blockIdx.x * 4 + w;
    if (p >= npair) return;
    long t = p / 12;
    int h = (int)(p - t * 12);
    float v = bf2f(Qb[t * HIDN + h * 64 + lane]) * bk[h * 64 + lane];
    for (int o = 32; o; o >>= 1) v += __shfl_down(v, o);
    if (lane == 0) qbk[p] = v;
}

// ---------------- fused attention v5 ----------------
// LDS diet (5 blocks/CU):
//   c_s : 8 rows x LDP(=776) bf16 (padded, staged via VALU convert)  = 12416 B
//   qk_s: 12 rows x 768 bf16, UNPADDED, 16B-chunk XOR-swizzle        = 18432 B
//         (staged async via global_load_lds w/ pre-swizzled source — m173)
//   scr : 16x16 f32 scores, re-used for softmax weights              =  1024 B
// MFMA fragment rows 12-15 / 8-15 are clamped to the last valid row instead
// of pad rows (garbage lands only in discarded C rows/cols).
// The fp32 candidate values loaded in phase 1b are CARRIED IN REGISTERS
// (cf[6] float4) and written to the fp32 repack region in phase 3 — no LDS
// re-read, no bf16 round-trip; cw consumes exact fp32 c.
#define LDP 776
__global__ __launch_bounds__(256) void attn_kernel(
    const float* __restrict__ cands, unsigned short* __restrict__ qkcw,
    const void* __restrict__ maskp, const int* __restrict__ flags,
    const float* __restrict__ qbk, float* __restrict__ allm, long t0) {
    const int tid = threadIdx.x;
    const long tl = blockIdx.x;
    const long t = t0 + tl;
    __shared__ __attribute__((aligned(16))) unsigned short buf[8 * LDP + 12 * HIDN];
    unsigned short* c_s = buf;
    unsigned short* qk_s = buf + 8 * LDP;
    __shared__ float scr[16][16];
    __shared__ int msk[NCAND];
    __shared__ float qb_s[NHEAD];

    // ---- phase 1a: issue async qk stage first (overlaps with c convert) ----
    const unsigned short* qsrc = qkcw + tl * (NHEAD * HIDN);
#pragma unroll
    for (int p = 0; p < 5; p++) {
        int i = tid + p * 256;  // 16B chunk index, 1152 total
        if (i < NHEAD * HIDN / 8) {
            int row = i / 96, cc = i - row * 96;
            int g = (cc & ~7) | ((cc & 7) ^ (row & 7));
            load_lds16(&qsrc[row * HIDN + g * 8], &qk_s[i * 8]);
        }
    }
    // ---- phase 1b: c fp32 global -> bf16 LDS, keep fp32 in registers ----
    const float4* c4 = (const float4*)(cands + t * NCAND * HIDN);
    float4 cf[6];
#pragma unroll
    for (int p = 0; p < 6; p++) {
        int i = tid + p * 256;  // 1536 float4s
        int n = i / 192, j4 = (i - n * 192) * 4;
        float4 f = c4[i];
        cf[p] = f;
        us4 o; o[0] = f2bf(f.x); o[1] = f2bf(f.y); o[2] = f2bf(f.z); o[3] = f2bf(f.w);
        *(us4*)&c_s[n * LDP + j4] = o;
    }
    if (tid < NCAND) {
        int mm = flags[0] ? 1 : (flags[1] ? 2 : (flags[2] ? 0 : 3));
        long mi = t * NCAND + tid;
        int mv;
        if (mm == 1)      mv = ((const unsigned char*)maskp)[mi] != 0;
        else if (mm == 2) mv = ((const float*)maskp)[mi] != 0.f;
        else if (mm == 3) mv = ((const long long*)maskp)[mi] != 0;
        else              mv = ((const int*)maskp)[mi] != 0;
        msk[tid] = mv;
    }
    if (tid >= 64 && tid < 64 + NHEAD) qb_s[tid - 64] = qbk[tl * NHEAD + (tid - 64)];
    __syncthreads();

    const int lane = tid & 63, w = tid >> 6;

    // ---- phase 2: scores via MFMA on wave 0: C[h][n] = qk[h,:] . c[n,:] ----
    if (w == 0) {
        int ar = lane & 15; if (ar > 11) ar = 11;  // clamp: rows 12-15 -> garbage C rows
        int br = lane & 15; if (br > 7) br = 7;    // clamp: cols 8-15 -> garbage C cols
        const int kq = lane >> 4;
        const unsigned short* brow = &c_s[br * LDP + kq * 8];
        f32x4 a0 = {}, a1 = {};
#pragma unroll
        for (int k0 = 0; k0 < HIDN; k0 += 64) {
            int c1 = (k0 >> 3) + kq, c2 = c1 + 4;
            int g1 = (c1 & ~7) | ((c1 & 7) ^ (ar & 7));
            int g2 = (c2 & ~7) | ((c2 & 7) ^ (ar & 7));
            bf16x8 afa = *(const bf16x8*)&qk_s[ar * HIDN + g1 * 8];
            bf16x8 afb = *(const bf16x8*)&qk_s[ar * HIDN + g2 * 8];
            bf16x8 bfa = *(const bf16x8*)&brow[k0];
            bf16x8 bfb = *(const bf16x8*)&brow[k0 + 32];
            a0 = __builtin_amdgcn_mfma_f32_16x16x32_bf16(afa, bfa, a0, 0, 0, 0);
            a1 = __builtin_amdgcn_mfma_f32_16x16x32_bf16(afb, bfb, a1, 0, 0, 0);
        }
        int n = lane & 15;
#pragma unroll
        for (int r = 0; r < 4; r++) {
            int h = (lane >> 4) * 4 + r;
            scr[h][n] = a0[r] + a1[r];
        }
    }
    if (tid == 64) {
        int a = 1;
        for (int n = 0; n < NCAND; n++) a &= msk[n];
        allm[tl] = a ? 0.f : 1.f;
    }
    __syncthreads();

    // ---- phase 3: softmax (12 threads) + fp32 repack of c from registers ----
    if (tid < NHEAD) {
        int h = tid;
        float sv[NCAND], sm = 0.f, mx = -1e30f;
        for (int n = 0; n < NCAND; n++) {
            sv[n] = msk[n] ? 1e-10f : (scr[h][n] + qb_s[h]) * 0.125f;
            mx = fmaxf(mx, sv[n]);
        }
        for (int n = 0; n < NCAND; n++) { sv[n] = expf(sv[n] - mx); sm += sv[n]; }
        float inv = 1.f / sm;
        for (int n = 0; n < NCAND; n++) scr[h][n] = sv[n] * inv;  // weights overlay scores
    }
    // c32[n*768 + j] linear == chunk index * 4 (since 768 = 192*4)
    float* c32 = (float*)buf;  // 6144 floats = 24576 B <= 30848 B (qk region dead)
#pragma unroll
    for (int p = 0; p < 6; p++) {
        int i = tid + p * 256;
        *(float4*)&c32[i * 4] = cf[p];
    }
    __syncthreads();

    // ---- phase 4: cw: out[h][j..j+7] = sum_n w[h][n] * c32[n][j..j+7] ----
    unsigned short* out = qkcw + tl * (NHEAD * HIDN);
#pragma unroll
    for (int p = 0; p < 5; p++) {
        int i = tid + p * 256;
        if (i < NHEAD * HIDN / 8) {
            int h = i / 96, j8 = (i - h * 96) * 8;
            f32x4 acc0 = {}, acc1 = {};
#pragma unroll
            for (int n = 0; n < NCAND; n++) {
                float a = scr[h][n];
                f32x4 v0 = *(const f32x4*)&c32[n * HIDN + j8];
                f32x4 v1 = *(const f32x4*)&c32[n * HIDN + j8 + 4];
#pragma unroll
                for (int k = 0; k < 4; k++) { acc0[k] += a * v0[k]; acc1[k] += a * v1[k]; }
            }
            us8 o;
#pragma unroll
            for (int k = 0; k < 4; k++) { o[k] = f2bf(acc0[k]); o[4 + k] = f2bf(acc1[k]); }
            *(us8*)&out[i * 8] = o;
        }
    }
}

// ---------------- residual + layernorm ----------------
__global__ __launch_bounds__(256) void ln_kernel(float* __restrict__ io, const float* __restrict__ x,
                                                 const float* __restrict__ gamma,
                                                 const float* __restrict__ beta, long t0) {
    const int tid = threadIdx.x;
    const long tl = blockIdx.x;
    const long t = t0 + tl;
    float* row = io + tl * HIDN;
    const float* xr = x + t * HIDN;
    float v[3];
#pragma unroll
    for (int i = 0; i < 3; i++) v[i] = row[tid + i * 256] + xr[tid + i * 256];
    __shared__ float red[4];
    const int lane = tid & 63, w = tid >> 6;
    float s = v[0] + v[1] + v[2];
    for (int o = 32; o; o >>= 1) s += __shfl_down(s, o);
    if (lane == 0) red[w] = s;
    __syncthreads();
    float mu = (red[0] + red[1] + red[2] + red[3]) * (1.f / HIDN);
    __syncthreads();
    float d0 = v[0] - mu, d1 = v[1] - mu, d2 = v[2] - mu;
    float q = d0 * d0 + d1 * d1 + d2 * d2;
    for (int o = 32; o; o >>= 1) q += __shfl_down(q, o);
    if (lane == 0) red[w] = q;
    __syncthreads();
    float var = (red[0] + red[1] + red[2] + red[3]) * (1.f / HIDN);
    float inv = rsqrtf(var + 1e-12f);
#pragma unroll
    for (int i = 0; i < 3; i++) {
        int j = tid + i * 256;
        row[j] = (v[i] - mu) * inv * gamma[j] + beta[j];
    }
}

// ---------------- launcher ----------------
extern "C" void kernel_launch(void* const* d_in, const int* in_sizes, int n_in,
                              void* d_out, int out_size, void* d_ws, size_t ws_size,
                              hipStream_t stream) {
    const float* x     = (const float*)d_in[0];
    const float* cands = (const float*)d_in[1];
    const void*  maskp = d_in[2];
    const float* Wq = (const float*)d_in[3];
    const float* bq = (const float*)d_in[4];
    const float* Wk = (const float*)d_in[5];
    const float* bk = (const float*)d_in[6];
    const float* Wv = (const float*)d_in[7];
    const float* bv = (const float*)d_in[8];
    const float* Wt = (const float*)d_in[9];
    const float* bt = (const float*)d_in[10];
    const float* Wc = (const float*)d_in[11];
    const float* bc = (const float*)d_in[12];
    const float* gamma = (const float*)d_in[13];
    const float* beta  = (const float*)d_in[14];
    float* out = (float*)d_out;

    const long T = (long)in_sizes[0] / HIDN;  // 8192

    char* p = (char*)d_ws;
    auto alloc = [&](size_t bytes) -> char* {
        char* r = p;
        p += (bytes + 255) & ~(size_t)255;
        return r;
    };
    unsigned short* Wqb  = (unsigned short*)alloc((size_t)HIDN * HIDN * 2);
    unsigned short* Wk2b = (unsigned short*)alloc((size_t)HIDN * HIDN * 2);
    unsigned short* Wvb  = (unsigned short*)alloc((size_t)HIDN * HIDN * 2);
    unsigned short* Wtb  = (unsigned short*)alloc((size_t)FFDIM * HIDN * 2);
    unsigned short* Wcb  = (unsigned short*)alloc((size_t)HIDN * FFDIM * 2);
    int* flags = (int*)alloc(256);
    size_t fixed = (size_t)(p - (char*)d_ws);

    long TC = T;
    auto chunk_bytes = [&](long tc) -> size_t {
        return (size_t)tc * (HIDN * 2 + HIDN * 2 + NHEAD * 4 + 4 +
                             HIDN * 2 + NHEAD * HIDN * 2) + 8 * 256;
    };
    while (TC > 512 && fixed + chunk_bytes(TC) > ws_size) TC >>= 1;

    unsigned short* Xb   = (unsigned short*)alloc((size_t)TC * HIDN * 2);
    unsigned short* Qb   = (unsigned short*)alloc((size_t)TC * HIDN * 2);
    float* qbkb          = (float*)alloc((size_t)TC * NHEAD * 4);
    float* allm          = (float*)alloc((size_t)TC * 4);
    unsigned short* CTXb = (unsigned short*)alloc((size_t)TC * HIDN * 2);
    unsigned short* BIG  = (unsigned short*)alloc((size_t)TC * NHEAD * HIDN * 2);

    {
        long n4;
        n4 = (long)HIDN * HIDN / 4;
        cvt_f2b<<<dim3((n4 + 255) / 256), 256, 0, stream>>>(Wq, Wqb, n4);
        cvt_f2b<<<dim3((n4 + 255) / 256), 256, 0, stream>>>(Wv, Wvb, n4);
        n4 = (long)FFDIM * HIDN / 4;
        cvt_f2b<<<dim3((n4 + 255) / 256), 256, 0, stream>>>(Wt, Wtb, n4);
        cvt_f2b<<<dim3((n4 + 255) / 256), 256, 0, stream>>>(Wc, Wcb, n4);
        cvt_wk<<<dim3(NHEAD * (HIDN / 64)), 256, 0, stream>>>(Wk, Wk2b);
        zero_flags<<<dim3(1), 64, 0, stream>>>(flags);
        mask_scan<<<dim3(256), 256, 0, stream>>>((const unsigned char*)maskp,
                                                 (int)(T * NCAND), flags);
    }

    for (long t0 = 0; t0 < T; t0 += TC) {
        long n4 = TC * HIDN / 4;
        cvt_f2b<<<dim3((n4 + 255) / 256), 256, 0, stream>>>(x + t0 * HIDN, Xb, n4);

        // G1: Q = X @ Wq^T + bq  (64x128 tile, 768 blocks = 3/CU)
        gemm128<true, false, 2><<<dim3(HIDN / 128, TC / 64, 1), 256, 0, stream>>>(
            Xb, Wqb, Qb, bq, HIDN, HIDN, HIDN, HIDN, 0, 0, 0);

        qbk_kernel<<<dim3((TC * NHEAD + 3) / 4), 256, 0, stream>>>(Qb, bk, qbkb, TC * NHEAD);

        // G2: qk_h = Q_h @ Wk_h  (per head, K=64; 128x128 tile, 4608 blocks)
        gemm128<true, false, 4><<<dim3(HIDN / 128, TC / 128, NHEAD), 256, 0, stream>>>(
            Qb, Wk2b, BIG, nullptr, HDIM, HIDN, HDIM, NHEAD * HIDN,
            HDIM, (long)HIDN * HDIM, HIDN);

        attn_kernel<<<dim3(TC), 256, 0, stream>>>(cands, BIG, maskp, flags, qbkb, allm, t0);

        // G5: ctx_h = cw_h @ Wv_h^T + bv_h (per head, N=64) — 128x64 async-staged
        gemm_n64<4><<<dim3(1, TC / 128, NHEAD), 256, 0, stream>>>(
            BIG, Wvb, CTXb, bv, allm, HIDN, NHEAD * HIDN, HIDN,
            HIDN, (long)HDIM * HIDN, HDIM, HDIM);

        // G6: h1 = gelu(ctx @ Wt^T + bt)
        gemm128<true, true, 4><<<dim3(FFDIM / 128, TC / 128, 1), 256, 0, stream>>>(
            CTXb, Wtb, BIG, bt, HIDN, HIDN, HIDN, FFDIM, 0, 0, 0);

        // G7: out = h1 @ Wc^T + bc (fp32)  (64x128 tile, 768 blocks = 3/CU)
        gemm128<false, false, 2><<<dim3(HIDN / 128, TC / 64, 1), 256, 0, stream>>>(
            BIG, Wcb, out + t0 * HIDN, bc, FFDIM, FFDIM, FFDIM, HIDN, 0, 0, 0);

        ln_kernel<<<dim3(TC), 256, 0, stream>>>(out + t0 * HIDN, x, gamma, beta, t0);
    }
}